// Round 4
// baseline (653.698 us; speedup 1.0000x reference)
//
#include <hip/hip_runtime.h>
#include <hip/hip_bf16.h>

// Problem constants (from reference)
#define N_ENC 500000
#define N_PAT 100000
#define N_TOT 600000
#define D 64
#define HID 128
#define NE 1000000

typedef unsigned short ushort_t;
typedef unsigned int uint_t;
typedef __attribute__((ext_vector_type(8))) short bfrag8;   // 8 x bf16 (4 VGPRs)
typedef __attribute__((ext_vector_type(4))) float f32x4;

// Workspace layout (float units). Zeroed region first (one small memset).
// Combined node space: enc = [0, 500000), pat = [500000, 600000).
// Combined edge space: pe edges = [0, 1M) of csr, ep edges = [1M, 2M).
#define OFF_HIST     0              // 600,000 ints (combined degree/histogram)
#define OFF_DEGCNT   600000         // 128 ints (64 enc + 64 pat buckets)
#define ZERO_FLOATS  600128         // ~2.4 MB zeroed
#define OFF_DEGCUR   600128         // 128 ints (bucket cursors)
#define OFF_EXCL     600256         // 600,000
#define OFF_PART     1200256        // 1,024
#define OFF_BASE     1201280        // 600,001 (pad 600,032)
#define OFF_CUR      1801312        // 600,000
#define OFF_PERM     2401312        // 600,000 (enc [0,500k), pat [500k,600k))
#define OFF_CSR      3001312        // 2,000,000 ints (combined, dst-sorted)
#define OFF_XBF_ENC  5001312        // 500,000*64 bf16 = 16,000,000 floats
#define OFF_XBF_PAT  21001312       // 100,000*64 bf16 = 3,200,000 floats
#define OFF_SPAT     24201312       // 100,000
#define OFF_FRAGS    24301312       // 4 matrices * 8192 ushort = 16,384 floats
#define OFF_WL2C     24317696       // 128
#define OFF_WR2C     24317824       // 128
#define OFF_C0       24317952       // 64
// end ~24.32M floats ~97.3 MB

__device__ inline ushort_t f2bf(float x) {
    // round-to-nearest-even f32 -> bf16
    uint_t u = __float_as_uint(x);
    u += 0x7fffu + ((u >> 16) & 1u);
    return (ushort_t)(u >> 16);
}

// ---------------- Prep (weights -> MFMA fragments; layer-2 collapse) --------
__global__ __launch_bounds__(256) void prep_kernel(
    const float* __restrict__ Wl_pe1, const float* __restrict__ Wr_pe1,
    const float* __restrict__ Wl_ep1, const float* __restrict__ Wr_ep1,
    const float* __restrict__ Wl_pe2, const float* __restrict__ Wr_pe2,
    const float* __restrict__ b_pe2, const float* __restrict__ Wc,
    const float* __restrict__ bc, float* __restrict__ ws)
{
    int t = blockIdx.x * blockDim.x + threadIdx.x;
    const int total = 4 * 8192;
    ushort_t* fr = (ushort_t*)(ws + OFF_FRAGS);
    for (int i = t; i < total; i += gridDim.x * blockDim.x) {
        int mtx = i >> 13;
        int r = i & 8191;
        int jj = r & 7;
        int l = (r >> 3) & 63;
        int ft = r >> 9;          // 0..15 = jt*2+kt
        int kt = ft & 1;
        int jt = ft >> 1;
        int k = kt * 32 + (l >> 4) * 8 + jj;
        int j = jt * 16 + (l & 15);
        const float* W = (mtx == 0) ? Wl_pe1 : (mtx == 1) ? Wr_pe1
                       : (mtx == 2) ? Wl_ep1 : Wr_ep1;
        fr[i] = f2bf(W[k * HID + j]);
    }
    if (blockIdx.x == 0) {
        int tid = threadIdx.x;
        if (tid < HID) {
            float s1 = 0.f, s2 = 0.f;
            for (int j = 0; j < HID; j++) {
                float wc = Wc[j];
                s1 += Wl_pe2[tid * HID + j] * wc;
                s2 += Wr_pe2[tid * HID + j] * wc;
            }
            ws[OFF_WL2C + tid] = s1;
            ws[OFF_WR2C + tid] = s2;
            if (tid == 0) {
                float c0 = bc[0];
                for (int j = 0; j < HID; j++) c0 += b_pe2[j] * Wc[j];
                ws[OFF_C0] = c0;
            }
        }
    }
}

// f32 -> bf16 conversion for BOTH feature matrices, grid-strided (low WG count)
__global__ __launch_bounds__(256) void cvt_bf16_all_kernel(
    const float* __restrict__ x_enc, const float* __restrict__ x_pat,
    ushort_t* __restrict__ xbf_enc, ushort_t* __restrict__ xbf_pat)
{
    const int n8_enc = N_ENC * D / 8;            // 4,000,000
    const int n8_tot = n8_enc + N_PAT * D / 8;   // 4,800,000
    int stride = gridDim.x * 256;
    for (int i = blockIdx.x * 256 + threadIdx.x; i < n8_tot; i += stride) {
        const float* in; ushort_t* outp; int j;
        if (i < n8_enc) { in = x_enc; outp = xbf_enc; j = i; }
        else            { in = x_pat; outp = xbf_pat; j = i - n8_enc; }
        const f32x4* p = (const f32x4*)(in + (size_t)j * 8);
        f32x4 v0 = p[0], v1 = p[1];
        uint4 o;
        o.x = (uint_t)f2bf(v0[0]) | ((uint_t)f2bf(v0[1]) << 16);
        o.y = (uint_t)f2bf(v0[2]) | ((uint_t)f2bf(v0[3]) << 16);
        o.z = (uint_t)f2bf(v1[0]) | ((uint_t)f2bf(v1[1]) << 16);
        o.w = (uint_t)f2bf(v1[2]) | ((uint_t)f2bf(v1[3]) << 16);
        *(uint4*)(outp + (size_t)j * 8) = o;
    }
}

// ---------------- CSR build (combined 600k-node space) ----------------------

__global__ __launch_bounds__(256) void hist_all_kernel(
    const int* __restrict__ dst_pe, const int* __restrict__ dst_ep,
    int* __restrict__ hist)
{
    int stride = gridDim.x * 256;
    for (int e = blockIdx.x * 256 + threadIdx.x; e < 2 * NE; e += stride) {
        int node = (e < NE) ? dst_pe[e] : N_ENC + dst_ep[e - NE];
        atomicAdd(&hist[node], 1);
    }
}

__global__ __launch_bounds__(1024) void scan_block_kernel(
    const int* __restrict__ in, int n, int* __restrict__ excl,
    int* __restrict__ partials)
{
    __shared__ int buf[1024];
    int t = threadIdx.x;
    int g = blockIdx.x * 1024 + t;
    int v = (g < n) ? in[g] : 0;
    buf[t] = v;
    __syncthreads();
    for (int off = 1; off < 1024; off <<= 1) {
        int u = (t >= off) ? buf[t - off] : 0;
        __syncthreads();
        buf[t] += u;
        __syncthreads();
    }
    if (g < n) excl[g] = buf[t] - v;
    if (t == 1023) partials[blockIdx.x] = buf[t];
}

__global__ __launch_bounds__(1024) void scan_partials_kernel(
    int* __restrict__ partials, int np)
{
    __shared__ int buf[1024];
    int t = threadIdx.x;
    int v = (t < np) ? partials[t] : 0;
    buf[t] = v;
    __syncthreads();
    for (int off = 1; off < 1024; off <<= 1) {
        int u = (t >= off) ? buf[t - off] : 0;
        __syncthreads();
        buf[t] += u;
        __syncthreads();
    }
    if (t < np) partials[t] = buf[t] - v;
}

__global__ __launch_bounds__(256) void scan_final_kernel(
    const int* __restrict__ excl, const int* __restrict__ partials, int n,
    int total, int* __restrict__ base, int* __restrict__ cur)
{
    int stride = gridDim.x * 256;
    for (int g = blockIdx.x * 256 + threadIdx.x; g <= n; g += stride) {
        if (g < n) {
            int v = excl[g] + partials[g >> 10];
            base[g] = v;
            cur[g] = v;
        } else {
            base[g] = total;
        }
    }
}

__global__ __launch_bounds__(256) void place_all_kernel(
    const int* __restrict__ src_pe, const int* __restrict__ dst_pe,
    const int* __restrict__ src_ep, const int* __restrict__ dst_ep,
    int* __restrict__ cur, int* __restrict__ csr)
{
    int stride = gridDim.x * 256;
    for (int e = blockIdx.x * 256 + threadIdx.x; e < 2 * NE; e += stride) {
        int node, val;
        if (e < NE) { node = dst_pe[e]; val = src_pe[e]; }
        else        { node = N_ENC + dst_ep[e - NE]; val = src_ep[e - NE]; }
        int pos = atomicAdd(&cur[node], 1);
        csr[pos] = val;
    }
}

// ---------------- Degree bucket sort (descending) ---------------------------
// Makes each transform wave degree-uniform (fewer gather rounds) and fronts
// the heavy waves. LDS histogram avoids same-address global-atomic storms.

__global__ __launch_bounds__(256) void degcnt_kernel(
    const int* __restrict__ hist, int* __restrict__ degcnt)
{
    __shared__ int h[128];
    int t = threadIdx.x;
    if (t < 128) h[t] = 0;
    __syncthreads();
    for (int i = blockIdx.x * 256 + t; i < N_TOT; i += gridDim.x * 256) {
        int d = hist[i];
        int b = (i < N_ENC ? 0 : 64) + (d < 63 ? d : 63);
        atomicAdd(&h[b], 1);
    }
    __syncthreads();
    if (t < 128 && h[t]) atomicAdd(&degcnt[t], h[t]);
}

__global__ void degscan_kernel(const int* __restrict__ degcnt,
                               int* __restrict__ degcur)
{
    // trivial 64-element descending exclusive scans; 1 block, serial
    if (threadIdx.x == 0) {
        int acc = 0;
        for (int d = 63; d >= 0; --d) { degcur[d] = acc; acc += degcnt[d]; }
    } else if (threadIdx.x == 1) {
        int acc = N_ENC;   // pat perm section starts at 500,000
        for (int d = 63; d >= 0; --d) { degcur[64 + d] = acc; acc += degcnt[64 + d]; }
    }
}

// grid-strided; per 256-node chunk: LDS rank + one global atomic per bucket
__global__ __launch_bounds__(256) void permplace_kernel(
    const int* __restrict__ hist, int* __restrict__ degcur,
    int* __restrict__ perm)
{
    __shared__ int h[128];
    __shared__ int g[128];
    int t = threadIdx.x;
    int stride = gridDim.x * 256;
    for (int i0 = blockIdx.x * 256; i0 < N_TOT; i0 += stride) {
        int i = i0 + t;
        if (t < 128) h[t] = 0;
        __syncthreads();
        int b = -1, rank = 0, nid = 0;
        if (i < N_TOT) {
            int d = hist[i];
            b = (i < N_ENC ? 0 : 64) + (d < 63 ? d : 63);
            nid = (i < N_ENC) ? i : i - N_ENC;
            rank = atomicAdd(&h[b], 1);
        }
        __syncthreads();
        if (t < 128 && h[t]) g[t] = atomicAdd(&degcur[t], h[t]);
        __syncthreads();
        if (i < N_TOT) perm[g[b] + rank] = nid;
        __syncthreads();   // protect h/g before next chunk re-zeroes
    }
}

// ---------------- Fused gather + MFMA transform (persistent waves) ----------
// One wave-group = 16 nodes (degree-sorted via perm). Persistent: each wave
// grid-strides over groups -- the r0-r3 profiles showed duration invariant
// under per-wave ILP changes with all pipes <35% busy and occupancy stuck at
// ~40% despite VGPR=56: the limit is workgroup churn (short waves, 7.8k WGs),
// not in-wave latency. Persistent waves keep CUs full.
//
// Gather is degree-adaptive (waves are degree-uniform after the sort):
//   maxdeg<=2 -> single depth-2 round (no clamped-duplicate row loads)
//   else      -> depth-4 batched rounds (r1 form)
// sval gather only on q==0 lanes (the only lanes whose sa is consumed).
//   zL = sum_edges x_src @ Wl ; zR = x_dst @ Wr
//   z  = zL*invc + zR + bias ; out = sum_j relu(z)*cvec[j] (+ sa*invc + c0)
// A-frag: lane holds A[m=lane&15][k=(lane>>4)*8+jj]
// B-frag: lane holds B[k=(lane>>4)*8+jj][n=lane&15] (pre-packed)
// C/D: col(j)=lane&15, row(node)=(lane>>4)*4+reg (m89/m91-verified)
// NOTE: do NOT add __launch_bounds__ min-waves: (256,8) forced scratch spill
// (VGPR 32, WRITE_SIZE 2MB->252MB, +57us -- round-2 lesson).
__global__ __launch_bounds__(256) void transform_fused_kernel(
    const ushort_t* __restrict__ xsrc, const int* __restrict__ csr,
    const int* __restrict__ base, const ushort_t* __restrict__ xdst,
    const int* __restrict__ perm,
    const ushort_t* __restrict__ fragWl, const ushort_t* __restrict__ fragWr,
    const float* __restrict__ bias, const float* __restrict__ cvec,
    const float* __restrict__ sval, const float* __restrict__ c0p,
    float* __restrict__ out, int nwaves, int add_extra)
{
    int l = threadIdx.x & 63;
    int m = l & 15;
    int q = l >> 4;
    int wstride = gridDim.x * 4;

    for (int wid = blockIdx.x * 4 + (threadIdx.x >> 6); wid < nwaves;
         wid += wstride) {
        int nb = wid * 16;
        int row = perm[nb + m];          // degree-sorted node id

        int s0 = base[row], s1 = base[row + 1];
        int deg = s1 - s0;
        float degf = (float)deg;

        // dst-feature frags: issued before the gather so they fly under it
        const ushort_t* xd = xdst + (size_t)row * D;
        bfrag8 x0 = *(const bfrag8*)(xd + q * 8);
        bfrag8 x1 = *(const bfrag8*)(xd + 32 + q * 8);

        float bias_v[8], cvec_v[8];
#pragma unroll
        for (int jt = 0; jt < 8; jt++) {
            bias_v[jt] = bias[jt * 16 + m];
            cvec_v[jt] = cvec[jt * 16 + m];
        }

        // wave-uniform max degree (width 16 covers all m; q-groups identical)
        int maxd = deg;
#pragma unroll
        for (int off = 1; off < 16; off <<= 1)
            maxd = max(maxd, __shfl_xor(maxd, off, 16));

        float accf[16];
#pragma unroll
        for (int i = 0; i < 16; i++) accf[i] = 0.f;
        float sa = 0.f;

        auto acc8 = [&](uint4 A, uint4 B) {
            uint_t dw[8] = {A.x, A.y, A.z, A.w, B.x, B.y, B.z, B.w};
#pragma unroll
            for (int k = 0; k < 8; k++) {
                accf[2 * k]     += __uint_as_float(dw[k] << 16);
                accf[2 * k + 1] += __uint_as_float(dw[k] & 0xffff0000u);
            }
        };

        if (maxd <= 2) {
            // deg 0/1/2: one round, no clamped duplicate loads
            if (deg > 0) {
                int si0 = csr[s0];
                int si1 = csr[s1 - 1];      // == si0 when deg==1
                const uint_t* xr0 = (const uint_t*)(xsrc + (size_t)si0 * D);
                uint4 w00 = *(const uint4*)(xr0 + q * 4);
                uint4 w01 = *(const uint4*)(xr0 + 16 + q * 4);
                float sv0 = 0.f, sv1 = 0.f;
                if (add_extra && q == 0) sv0 = sval[si0];
                if (deg > 1) {
                    const uint_t* xr1 = (const uint_t*)(xsrc + (size_t)si1 * D);
                    uint4 w10 = *(const uint4*)(xr1 + q * 4);
                    uint4 w11 = *(const uint4*)(xr1 + 16 + q * 4);
                    if (add_extra && q == 0) sv1 = sval[si1];
                    acc8(w10, w11);
                    sa += sv1;
                }
                acc8(w00, w01);
                sa += sv0;
            }
        } else {
            int s1m1 = s1 - 1;
            for (int e = s0; e < s1; e += 4) {
                int sidx[4];
#pragma unroll
                for (int i = 0; i < 4; i++) {
                    int ee = e + i;
                    sidx[i] = csr[ee < s1m1 ? ee : s1m1];
                }
                uint4 w0[4], w1[4];
                float sv[4];
#pragma unroll
                for (int i = 0; i < 4; i++) {
                    const uint_t* xr = (const uint_t*)(xsrc + (size_t)sidx[i] * D);
                    w0[i] = *(const uint4*)(xr + q * 4);
                    w1[i] = *(const uint4*)(xr + 16 + q * 4);
                    sv[i] = (add_extra && q == 0) ? sval[sidx[i]] : 0.f;
                }
#pragma unroll
                for (int i = 0; i < 4; i++) {
                    if (e + i < s1) {
                        acc8(w0[i], w1[i]);
                        sa += sv[i];
                    }
                }
            }
        }

        bfrag8 a0, a1;
#pragma unroll
        for (int i = 0; i < 8; i++) {
            a0[i] = (short)f2bf(accf[i]);
            a1[i] = (short)f2bf(accf[8 + i]);
        }

        // invc for the 4 C-rows (wave slots nb+q*4+r) this lane holds
        f32x4 invc4;
#pragma unroll
        for (int r = 0; r < 4; r++) {
            float dg = __shfl(degf, q * 4 + r);  // lanes 0..15 hold slot degs
            invc4[r] = 1.0f / fmaxf(dg, 1.0f);
        }

        f32x4 p = {0.f, 0.f, 0.f, 0.f};
#pragma unroll
        for (int jt = 0; jt < 8; jt++) {
            const bfrag8* bl0 = (const bfrag8*)(fragWl + ((size_t)(jt * 2 + 0) * 64 + l) * 8);
            const bfrag8* bl1 = (const bfrag8*)(fragWl + ((size_t)(jt * 2 + 1) * 64 + l) * 8);
            const bfrag8* br0 = (const bfrag8*)(fragWr + ((size_t)(jt * 2 + 0) * 64 + l) * 8);
            const bfrag8* br1 = (const bfrag8*)(fragWr + ((size_t)(jt * 2 + 1) * 64 + l) * 8);
            f32x4 accl = {0.f, 0.f, 0.f, 0.f};
            f32x4 accr = {0.f, 0.f, 0.f, 0.f};
            accl = __builtin_amdgcn_mfma_f32_16x16x32_bf16(a0, *bl0, accl, 0, 0, 0);
            accl = __builtin_amdgcn_mfma_f32_16x16x32_bf16(a1, *bl1, accl, 0, 0, 0);
            accr = __builtin_amdgcn_mfma_f32_16x16x32_bf16(x0, *br0, accr, 0, 0, 0);
            accr = __builtin_amdgcn_mfma_f32_16x16x32_bf16(x1, *br1, accr, 0, 0, 0);
            float bj = bias_v[jt], cj = cvec_v[jt];
#pragma unroll
            for (int r = 0; r < 4; r++) {
                float z = accl[r] * invc4[r] + accr[r] + bj;
                p[r] += fmaxf(z, 0.f) * cj;
            }
        }
#pragma unroll
        for (int off = 1; off < 16; off <<= 1) {
            p[0] += __shfl_xor(p[0], off, 16);
            p[1] += __shfl_xor(p[1], off, 16);
            p[2] += __shfl_xor(p[2], off, 16);
            p[3] += __shfl_xor(p[3], off, 16);
        }
        // scalar sums + output rows for this quad's 4 slots (shuffles OUTSIDE
        // the divergent branch: source lanes m!=0 must be active)
        f32x4 sa4;
        int orow[4];
#pragma unroll
        for (int r = 0; r < 4; r++) {
            sa4[r] = __shfl(sa, q * 4 + r);
            orow[r] = __shfl(row, q * 4 + r);
        }
        if (m == 0) {
            float c0 = add_extra ? c0p[0] : 0.f;
#pragma unroll
            for (int r = 0; r < 4; r++) {
                float o = p[r];
                if (add_extra) o += sa4[r] * invc4[r] + c0;
                out[orow[r]] = o;   // scattered scalar store (perm order)
            }
        }
    }
}

extern "C" void kernel_launch(void* const* d_in, const int* in_sizes, int n_in,
                              void* d_out, int out_size, void* d_ws, size_t ws_size,
                              hipStream_t stream)
{
    const float* x_enc  = (const float*)d_in[0];
    const float* x_pat  = (const float*)d_in[1];
    const int*   src_pe = (const int*)d_in[2];
    const int*   dst_pe = (const int*)d_in[3];
    const int*   src_ep = (const int*)d_in[4];
    const int*   dst_ep = (const int*)d_in[5];
    const float* Wl_pe1 = (const float*)d_in[6];
    const float* Wr_pe1 = (const float*)d_in[7];
    const float* b_pe1  = (const float*)d_in[8];
    const float* Wl_ep1 = (const float*)d_in[9];
    const float* Wr_ep1 = (const float*)d_in[10];
    const float* b_ep1  = (const float*)d_in[11];
    const float* Wl_pe2 = (const float*)d_in[12];
    const float* Wr_pe2 = (const float*)d_in[13];
    const float* b_pe2  = (const float*)d_in[14];
    const float* Wc = (const float*)d_in[18];
    const float* bc = (const float*)d_in[19];

    float* ws  = (float*)d_ws;
    float* out = (float*)d_out;

    // zero: combined histogram + degree buckets (~2.4 MB)
    hipMemsetAsync(d_ws, 0, (size_t)ZERO_FLOATS * sizeof(float), stream);

    prep_kernel<<<128, 256, 0, stream>>>(Wl_pe1, Wr_pe1, Wl_ep1, Wr_ep1,
                                         Wl_pe2, Wr_pe2, b_pe2, Wc, bc, ws);

    int* hist   = (int*)(ws + OFF_HIST);
    int* degcnt = (int*)(ws + OFF_DEGCNT);
    int* degcur = (int*)(ws + OFF_DEGCUR);
    int* excl   = (int*)(ws + OFF_EXCL);
    int* part   = (int*)(ws + OFF_PART);
    int* basep  = (int*)(ws + OFF_BASE);
    int* cur    = (int*)(ws + OFF_CUR);
    int* perm   = (int*)(ws + OFF_PERM);
    int* csr    = (int*)(ws + OFF_CSR);
    ushort_t* xbf_enc = (ushort_t*)(ws + OFF_XBF_ENC);
    ushort_t* xbf_pat = (ushort_t*)(ws + OFF_XBF_PAT);

    // bf16 feature copies (one grid-strided kernel for both)
    cvt_bf16_all_kernel<<<2048, 256, 0, stream>>>(x_enc, x_pat, xbf_enc, xbf_pat);

    // combined histogram over 600k nodes / 2M edges
    hist_all_kernel<<<2048, 256, 0, stream>>>(dst_pe, dst_ep, hist);

    // combined scan -> base/cur (enc section first, then pat; csr is combined)
    int nb = (N_TOT + 1023) / 1024;   // 587
    scan_block_kernel<<<nb, 1024, 0, stream>>>(hist, N_TOT, excl, part);
    scan_partials_kernel<<<1, 1024, 0, stream>>>(part, nb);
    scan_final_kernel<<<1024, 256, 0, stream>>>(excl, part, N_TOT, 2 * NE,
                                                basep, cur);

    // degree bucket sort (reads hist; independent of scan outputs)
    degcnt_kernel<<<512, 256, 0, stream>>>(hist, degcnt);
    degscan_kernel<<<1, 64, 0, stream>>>(degcnt, degcur);
    permplace_kernel<<<1024, 256, 0, stream>>>(hist, degcur, perm);

    // CSR edge placement (both relations, one grid-strided kernel)
    place_all_kernel<<<2048, 256, 0, stream>>>(src_pe, dst_pe, src_ep, dst_ep,
                                               cur, csr);

    const ushort_t* frags = (const ushort_t*)(ws + OFF_FRAGS);

    // patient transform (fused ep-gather) -> s_pat; Wl_ep1/Wr_ep1, cvec=wl2c
    int pat_waves = N_PAT / 16;   // 6250
    transform_fused_kernel<<<1024, 256, 0, stream>>>(
        xbf_enc, csr, basep + N_ENC, xbf_pat, perm + N_ENC,
        frags + 2 * 8192, frags + 3 * 8192, b_ep1, ws + OFF_WL2C,
        nullptr, nullptr, ws + OFF_SPAT, pat_waves, 0);

    // encounter transform (fused pe-gather + layer-2 scalar gather) -> logits
    int enc_waves = N_ENC / 16;   // 31250
    transform_fused_kernel<<<2048, 256, 0, stream>>>(
        xbf_pat, csr, basep, xbf_enc, perm,
        frags + 0 * 8192, frags + 1 * 8192, b_pe1, ws + OFF_WR2C,
        ws + OFF_SPAT, ws + OFF_C0, out, enc_waves, 1);
}

// Round 6
// 505.136 us; speedup vs baseline: 1.2941x; 1.2941x over previous
//
#include <hip/hip_runtime.h>
#include <hip/hip_bf16.h>

// Problem constants (from reference)
#define N_ENC 500000
#define N_PAT 100000
#define N_TOT 600000
#define D 64
#define HID 128
#define NE 1000000

// CSR-build binning geometry.
// enc buckets: 2048 nodes each (deg~2 -> mean 4096 edges/bucket, sd ~64)
// pat buckets: 512 nodes each (deg~10 -> mean 5120 edges/bucket, sd ~72)
// CAP 8192 is mean + >40 sd for both: overflow statistically impossible.
#define NB_ENC 245          // ceil(500000/2048)
#define NB 441              // 245 enc + 196 pat (ceil(100000/512))
#define CAP 8192            // per-bucket capacity (entries)
#define CH 8192             // edges per bin-kernel block

typedef unsigned short ushort_t;
typedef unsigned int uint_t;
typedef __attribute__((ext_vector_type(8))) short bfrag8;   // 8 x bf16 (4 VGPRs)
typedef __attribute__((ext_vector_type(4))) float f32x4;

// Workspace layout (float units). Zeroed region first (one tiny memset).
// r5 lesson: previous attempt ended at 25.53M floats (102 MB) -> workspace
// overrun -> device fault. This layout's high-water mark is 21.92M floats
// (87.7 MB), below the proven-good 24.32M (97.3 MB).
// KEY ALIASING: bin overlays the head of xbf_enc. bin is live only during
// bin->csrbuild; xbf_enc is written by cvt AFTER csrbuild (stream-ordered).
#define OFF_CURSOR   0              // NB ints (bucket fill cursors; pad 512)
#define ZERO_FLOATS  512
#define OFF_BBASE    512            // NB+1 ints (pad 512)
#define OFF_BASE     1024           // 600,001 ints (pad 600,032)
#define OFF_CSR      601056         // 2,000,000 ints
#define OFF_XBF_ENC  2601056        // 500,000*64 bf16 = 16,000,000 floats
#define OFF_BIN      2601056        // aliases xbf_enc head: 441*8192 = 3,612,672
#define OFF_XBF_PAT  18601056       // 100,000*64 bf16 = 3,200,000 floats
#define OFF_SPAT     21801056       // 100,000
#define OFF_FRAGS    21901056       // 4 matrices * 8192 ushort = 16,384 floats
#define OFF_WL2C     21917440       // 128
#define OFF_WR2C     21917568       // 128
#define OFF_C0       21917696       // 64
// end 21,917,760 floats = 87.7 MB

__device__ inline ushort_t f2bf(float x) {
    // round-to-nearest-even f32 -> bf16
    uint_t u = __float_as_uint(x);
    u += 0x7fffu + ((u >> 16) & 1u);
    return (ushort_t)(u >> 16);
}

// ---------------- Prep (weights -> MFMA fragments; layer-2 collapse) --------
__global__ __launch_bounds__(256) void prep_kernel(
    const float* __restrict__ Wl_pe1, const float* __restrict__ Wr_pe1,
    const float* __restrict__ Wl_ep1, const float* __restrict__ Wr_ep1,
    const float* __restrict__ Wl_pe2, const float* __restrict__ Wr_pe2,
    const float* __restrict__ b_pe2, const float* __restrict__ Wc,
    const float* __restrict__ bc, float* __restrict__ ws)
{
    int t = blockIdx.x * blockDim.x + threadIdx.x;
    const int total = 4 * 8192;
    ushort_t* fr = (ushort_t*)(ws + OFF_FRAGS);
    for (int i = t; i < total; i += gridDim.x * blockDim.x) {
        int mtx = i >> 13;
        int r = i & 8191;
        int jj = r & 7;
        int l = (r >> 3) & 63;
        int ft = r >> 9;          // 0..15 = jt*2+kt
        int kt = ft & 1;
        int jt = ft >> 1;
        int k = kt * 32 + (l >> 4) * 8 + jj;
        int j = jt * 16 + (l & 15);
        const float* W = (mtx == 0) ? Wl_pe1 : (mtx == 1) ? Wr_pe1
                       : (mtx == 2) ? Wl_ep1 : Wr_ep1;
        fr[i] = f2bf(W[k * HID + j]);
    }
    if (blockIdx.x == 0) {
        int tid = threadIdx.x;
        if (tid < HID) {
            float s1 = 0.f, s2 = 0.f;
            for (int j = 0; j < HID; j++) {
                float wc = Wc[j];
                s1 += Wl_pe2[tid * HID + j] * wc;
                s2 += Wr_pe2[tid * HID + j] * wc;
            }
            ws[OFF_WL2C + tid] = s1;
            ws[OFF_WR2C + tid] = s2;
            if (tid == 0) {
                float c0 = bc[0];
                for (int j = 0; j < HID; j++) c0 += b_pe2[j] * Wc[j];
                ws[OFF_C0] = c0;
            }
        }
    }
}

// f32 -> bf16 conversion for BOTH feature matrices, grid-strided.
// MUST run after csrbuild (xbf_enc aliases the bin staging region).
__global__ __launch_bounds__(256) void cvt_bf16_all_kernel(
    const float* __restrict__ x_enc, const float* __restrict__ x_pat,
    ushort_t* __restrict__ xbf_enc, ushort_t* __restrict__ xbf_pat)
{
    const int n8_enc = N_ENC * D / 8;            // 4,000,000
    const int n8_tot = n8_enc + N_PAT * D / 8;   // 4,800,000
    int stride = gridDim.x * 256;
    for (int i = blockIdx.x * 256 + threadIdx.x; i < n8_tot; i += stride) {
        const float* in; ushort_t* outp; int j;
        if (i < n8_enc) { in = x_enc; outp = xbf_enc; j = i; }
        else            { in = x_pat; outp = xbf_pat; j = i - n8_enc; }
        const f32x4* p = (const f32x4*)(in + (size_t)j * 8);
        f32x4 v0 = p[0], v1 = p[1];
        uint4 o;
        o.x = (uint_t)f2bf(v0[0]) | ((uint_t)f2bf(v0[1]) << 16);
        o.y = (uint_t)f2bf(v0[2]) | ((uint_t)f2bf(v0[3]) << 16);
        o.z = (uint_t)f2bf(v1[0]) | ((uint_t)f2bf(v1[1]) << 16);
        o.w = (uint_t)f2bf(v1[2]) | ((uint_t)f2bf(v1[3]) << 16);
        *(uint4*)(outp + (size_t)j * 8) = o;
    }
}

// ---------------- CSR build via LDS-staged two-phase binning ----------------
// r4 lesson: scattered 4B csr stores cost a full 64B HBM line each
// (place_all: WRITE_SIZE 133MB for 8MB useful, 183us). Fix: stage in LDS,
// write only contiguous runs. Phase 1 bins edges into 441 coarse dst-range
// buckets; phase 2 counting-sorts each bucket in LDS and writes the final
// csr segment + base[] offsets fully coalesced. Replaces hist + 3-stage
// 600k scan + place entirely (bucket prefix = 441-elem scan).
// Entry packing: src (20 bits, <1M) | dst-local (<=11 bits) << 20.

__global__ __launch_bounds__(256) void bin_kernel(
    const int* __restrict__ src_pe, const int* __restrict__ dst_pe,
    const int* __restrict__ src_ep, const int* __restrict__ dst_ep,
    int* __restrict__ cursor, uint_t* __restrict__ bin)
{
    __shared__ int lhist[512];     // padded to 512 for pair-scan
    __shared__ int lbase[512];
    __shared__ int lcnt2[NB];
    __shared__ int gpos[NB];
    __shared__ int s[256];
    __shared__ uint_t lout[CH];
    int t = threadIdx.x;
    int e0 = blockIdx.x * CH;
    int n = min(CH, 2 * NE - e0);

    for (int i = t; i < 512; i += 256) lhist[i] = 0;
    for (int i = t; i < NB; i += 256) lcnt2[i] = 0;   // r5 bugfix: all NB=441
    __syncthreads();
    // pass A: bucket histogram (dst only)
    for (int i = t; i < n; i += 256) {
        int e = e0 + i;
        int dc = (e < NE) ? dst_pe[e] : N_ENC + dst_ep[e - NE];
        int b = (dc < N_ENC) ? (dc >> 11) : (NB_ENC + ((dc - N_ENC) >> 9));
        atomicAdd(&lhist[b], 1);
    }
    __syncthreads();
    // exclusive scan of lhist[0..511]: pair-compress to 256 + Hillis-Steele
    int a0 = lhist[2 * t], a1 = lhist[2 * t + 1];
    s[t] = a0 + a1;
    __syncthreads();
    for (int off = 1; off < 256; off <<= 1) {
        int u = (t >= off) ? s[t - off] : 0;
        __syncthreads();
        s[t] += u;
        __syncthreads();
    }
    int ex = s[t] - a0 - a1;
    lbase[2 * t] = ex;
    lbase[2 * t + 1] = ex + a0;
    __syncthreads();
    // reserve global space (one atomic per nonempty bucket per block)
    for (int b = t; b < NB; b += 256) {
        int c = lhist[b];
        if (c) gpos[b] = atomicAdd(&cursor[b], c);
    }
    __syncthreads();
    // pass B: scatter into LDS, bucket-sorted
    for (int i = t; i < n; i += 256) {
        int e = e0 + i;
        int dc, sv;
        if (e < NE) { dc = dst_pe[e]; sv = src_pe[e]; }
        else { dc = N_ENC + dst_ep[e - NE]; sv = src_ep[e - NE]; }
        int b, loc;
        if (dc < N_ENC) { b = dc >> 11; loc = dc & 2047; }
        else { b = NB_ENC + ((dc - N_ENC) >> 9); loc = (dc - N_ENC) & 511; }
        int r = atomicAdd(&lcnt2[b], 1);
        lout[lbase[b] + r] = (uint_t)sv | ((uint_t)loc << 20);
    }
    __syncthreads();
    // copy runs to global bucket regions (contiguous per run)
    int wv = t >> 6, ln = t & 63;
    for (int b = wv; b < NB; b += 4) {
        int c = lhist[b];
        if (!c) continue;
        int gp = gpos[b];
        int c2 = min(c, CAP - gp);   // defensive clamp (overflow ~impossible)
        if (c2 <= 0) continue;
        uint_t* dstp = bin + (size_t)b * CAP + gp;
        const uint_t* srcp = lout + lbase[b];
        for (int k = ln; k < c2; k += 64) dstp[k] = srcp[k];
    }
}

__global__ __launch_bounds__(256) void bucketscan_kernel(
    const int* __restrict__ cursor, int* __restrict__ bbase,
    int* __restrict__ base)
{
    __shared__ int s[256];
    __shared__ int c2[512];
    int t = threadIdx.x;
    for (int i = t; i < 512; i += 256) c2[i] = (i < NB) ? min(cursor[i], CAP) : 0;
    __syncthreads();
    int a0 = c2[2 * t], a1 = c2[2 * t + 1];
    s[t] = a0 + a1;
    __syncthreads();
    for (int off = 1; off < 256; off <<= 1) {
        int u = (t >= off) ? s[t - off] : 0;
        __syncthreads();
        s[t] += u;
        __syncthreads();
    }
    int ex = s[t] - a0 - a1;
    if (2 * t < NB) bbase[2 * t] = ex;
    if (2 * t + 1 < NB) bbase[2 * t + 1] = ex + a0;
    if (t == 255) { bbase[NB] = s[t]; base[N_TOT] = s[t]; }
}

// one block per bucket: LDS counting sort by exact dst; coalesced csr+base out
__global__ __launch_bounds__(256) void csrbuild_kernel(
    const uint_t* __restrict__ bin, const int* __restrict__ cursor,
    const int* __restrict__ bbase, int* __restrict__ base,
    int* __restrict__ csr)
{
    __shared__ int h[2048];
    __shared__ int nb_[2048];
    __shared__ int s[256];
    __shared__ uint_t lout[CAP];
    int b = blockIdx.x;
    int t = threadIdx.x;
    int cnt = min(cursor[b], CAP);
    int nodes_base, nnodes;
    if (b < NB_ENC) { nodes_base = b << 11; nnodes = min(2048, N_ENC - nodes_base); }
    else { nodes_base = N_ENC + ((b - NB_ENC) << 9); nnodes = min(512, N_TOT - nodes_base); }
    const uint_t* reg = bin + (size_t)b * CAP;

    for (int i = t; i < 2048; i += 256) h[i] = 0;
    __syncthreads();
    for (int i = t; i < cnt; i += 256) atomicAdd(&h[reg[i] >> 20], 1);
    __syncthreads();
    // exclusive scan of h[0..2047]: 8 serial per thread + block scan
    int loc[8];
    int sum = 0;
#pragma unroll
    for (int j = 0; j < 8; j++) { loc[j] = sum; sum += h[8 * t + j]; }
    s[t] = sum;
    __syncthreads();
    for (int off = 1; off < 256; off <<= 1) {
        int u = (t >= off) ? s[t - off] : 0;
        __syncthreads();
        s[t] += u;
        __syncthreads();
    }
    int ex = s[t] - sum;
#pragma unroll
    for (int j = 0; j < 8; j++) nb_[8 * t + j] = ex + loc[j];
    __syncthreads();
    // write global CSR row offsets for this bucket's nodes (coalesced)
    int gb = bbase[b];
    for (int i = t; i < nnodes; i += 256) base[nodes_base + i] = gb + nb_[i];
    // re-zero h as rank counters
    for (int i = t; i < 2048; i += 256) h[i] = 0;
    __syncthreads();
    for (int i = t; i < cnt; i += 256) {
        uint_t p = reg[i];
        int lc = p >> 20;
        int r = atomicAdd(&h[lc], 1);
        lout[nb_[lc] + r] = p & 0xFFFFFu;
    }
    __syncthreads();
    for (int k = t; k < cnt; k += 256) csr[gb + k] = (int)lout[k];
}

// ---------------- Fused gather + MFMA transform (persistent waves) ----------
// One wave-group = 16 consecutive nodes (identity order; r3 showed the degree
// sort is net-negative). Persistent grid-stride over groups: r1 measured
// 27.6% occupancy at VGPR=72 (reg limit would allow ~87%) -> short-wave
// dispatch drain; persistent waves stay resident and loop.
// Gather is depth-4 batched (r1 form, best measured): 4 csr loads, then 8
// row-loads in flight, then predicated accumulate.
//   zL = sum_edges x_src @ Wl ; zR = x_dst @ Wr
//   z  = zL*invc + zR + bias ; out = sum_j relu(z)*cvec[j] (+ sa*invc + c0)
// A-frag: lane holds A[m=lane&15][k=(lane>>4)*8+jj]
// B-frag: lane holds B[k=(lane>>4)*8+jj][n=lane&15] (pre-packed)
// C/D: col(j)=lane&15, row(node)=(lane>>4)*4+reg (m89/m91-verified)
// NOTE: no __launch_bounds__ min-waves: (256,8) forced scratch spill
// (VGPR 32, WRITE_SIZE 2MB->252MB, +57us -- round-2 lesson).
__global__ __launch_bounds__(256) void transform_fused_kernel(
    const ushort_t* __restrict__ xsrc, const int* __restrict__ csr,
    const int* __restrict__ base, const ushort_t* __restrict__ xdst,
    const ushort_t* __restrict__ fragWl, const ushort_t* __restrict__ fragWr,
    const float* __restrict__ bias, const float* __restrict__ cvec,
    const float* __restrict__ sval, const float* __restrict__ c0p,
    float* __restrict__ out, int nwaves, int add_extra)
{
    int l = threadIdx.x & 63;
    int m = l & 15;
    int q = l >> 4;
    int wstride = gridDim.x * 4;

    float bias_v[8], cvec_v[8];
#pragma unroll
    for (int jt = 0; jt < 8; jt++) {
        bias_v[jt] = bias[jt * 16 + m];
        cvec_v[jt] = cvec[jt * 16 + m];
    }
    float c0 = add_extra ? c0p[0] : 0.f;

    for (int wid = blockIdx.x * 4 + (threadIdx.x >> 6); wid < nwaves;
         wid += wstride) {
        int nb = wid * 16;
        int row = nb + m;

        int s0 = base[row], s1 = base[row + 1];
        float degf = (float)(s1 - s0);

        // dst-feature frags: issued before the gather so they fly under it
        const ushort_t* xd = xdst + (size_t)row * D;
        bfrag8 x0 = *(const bfrag8*)(xd + q * 8);
        bfrag8 x1 = *(const bfrag8*)(xd + 32 + q * 8);

        float accf[16];
#pragma unroll
        for (int i = 0; i < 16; i++) accf[i] = 0.f;
        float sa = 0.f;

        int s1m1 = s1 - 1;
        for (int e = s0; e < s1; e += 4) {
            int sidx[4];
#pragma unroll
            for (int i = 0; i < 4; i++) {
                int ee = e + i;
                sidx[i] = csr[ee < s1m1 ? ee : s1m1];
            }
            uint4 w0[4], w1[4];
            float sv[4];
#pragma unroll
            for (int i = 0; i < 4; i++) {
                const uint_t* xr = (const uint_t*)(xsrc + (size_t)sidx[i] * D);
                w0[i] = *(const uint4*)(xr + q * 4);
                w1[i] = *(const uint4*)(xr + 16 + q * 4);
                sv[i] = (add_extra && q == 0) ? sval[sidx[i]] : 0.f;
            }
#pragma unroll
            for (int i = 0; i < 4; i++) {
                if (e + i < s1) {
                    uint_t dw[8] = {w0[i].x, w0[i].y, w0[i].z, w0[i].w,
                                    w1[i].x, w1[i].y, w1[i].z, w1[i].w};
#pragma unroll
                    for (int k = 0; k < 8; k++) {
                        accf[2 * k]     += __uint_as_float(dw[k] << 16);
                        accf[2 * k + 1] += __uint_as_float(dw[k] & 0xffff0000u);
                    }
                    sa += sv[i];
                }
            }
        }

        bfrag8 a0, a1;
#pragma unroll
        for (int i = 0; i < 8; i++) {
            a0[i] = (short)f2bf(accf[i]);
            a1[i] = (short)f2bf(accf[8 + i]);
        }

        // invc for the 4 C-rows (nodes nb+q*4+r) this lane holds
        f32x4 invc4;
#pragma unroll
        for (int r = 0; r < 4; r++) {
            float dg = __shfl(degf, q * 4 + r);  // lanes 0..15 hold node degs
            invc4[r] = 1.0f / fmaxf(dg, 1.0f);
        }

        f32x4 p = {0.f, 0.f, 0.f, 0.f};
#pragma unroll
        for (int jt = 0; jt < 8; jt++) {
            const bfrag8* bl0 = (const bfrag8*)(fragWl + ((size_t)(jt * 2 + 0) * 64 + l) * 8);
            const bfrag8* bl1 = (const bfrag8*)(fragWl + ((size_t)(jt * 2 + 1) * 64 + l) * 8);
            const bfrag8* br0 = (const bfrag8*)(fragWr + ((size_t)(jt * 2 + 0) * 64 + l) * 8);
            const bfrag8* br1 = (const bfrag8*)(fragWr + ((size_t)(jt * 2 + 1) * 64 + l) * 8);
            f32x4 accl = {0.f, 0.f, 0.f, 0.f};
            f32x4 accr = {0.f, 0.f, 0.f, 0.f};
            accl = __builtin_amdgcn_mfma_f32_16x16x32_bf16(a0, *bl0, accl, 0, 0, 0);
            accl = __builtin_amdgcn_mfma_f32_16x16x32_bf16(a1, *bl1, accl, 0, 0, 0);
            accr = __builtin_amdgcn_mfma_f32_16x16x32_bf16(x0, *br0, accr, 0, 0, 0);
            accr = __builtin_amdgcn_mfma_f32_16x16x32_bf16(x1, *br1, accr, 0, 0, 0);
            float bj = bias_v[jt], cj = cvec_v[jt];
#pragma unroll
            for (int r = 0; r < 4; r++) {
                float z = accl[r] * invc4[r] + accr[r] + bj;
                p[r] += fmaxf(z, 0.f) * cj;
            }
        }
#pragma unroll
        for (int off = 1; off < 16; off <<= 1) {
            p[0] += __shfl_xor(p[0], off, 16);
            p[1] += __shfl_xor(p[1], off, 16);
            p[2] += __shfl_xor(p[2], off, 16);
            p[3] += __shfl_xor(p[3], off, 16);
        }
        // layer-2 scalar sums for this quad's 4 nodes (from lanes 0..15)
        f32x4 sa4;
#pragma unroll
        for (int r = 0; r < 4; r++) sa4[r] = __shfl(sa, q * 4 + r);
        if (m == 0) {
            int basen = nb + q * 4;
            f32x4 o = p;
            if (add_extra) {
#pragma unroll
                for (int r = 0; r < 4; r++)
                    o[r] += sa4[r] * invc4[r] + c0;
            }
            *(f32x4*)(out + basen) = o;   // coalesced vector store
        }
    }
}

extern "C" void kernel_launch(void* const* d_in, const int* in_sizes, int n_in,
                              void* d_out, int out_size, void* d_ws, size_t ws_size,
                              hipStream_t stream)
{
    const float* x_enc  = (const float*)d_in[0];
    const float* x_pat  = (const float*)d_in[1];
    const int*   src_pe = (const int*)d_in[2];
    const int*   dst_pe = (const int*)d_in[3];
    const int*   src_ep = (const int*)d_in[4];
    const int*   dst_ep = (const int*)d_in[5];
    const float* Wl_pe1 = (const float*)d_in[6];
    const float* Wr_pe1 = (const float*)d_in[7];
    const float* b_pe1  = (const float*)d_in[8];
    const float* Wl_ep1 = (const float*)d_in[9];
    const float* Wr_ep1 = (const float*)d_in[10];
    const float* b_ep1  = (const float*)d_in[11];
    const float* Wl_pe2 = (const float*)d_in[12];
    const float* Wr_pe2 = (const float*)d_in[13];
    const float* b_pe2  = (const float*)d_in[14];
    const float* Wc = (const float*)d_in[18];
    const float* bc = (const float*)d_in[19];

    float* ws  = (float*)d_ws;
    float* out = (float*)d_out;

    // zero: bucket cursors only (2 KB)
    hipMemsetAsync(d_ws, 0, (size_t)ZERO_FLOATS * sizeof(float), stream);

    prep_kernel<<<128, 256, 0, stream>>>(Wl_pe1, Wr_pe1, Wl_ep1, Wr_ep1,
                                         Wl_pe2, Wr_pe2, b_pe2, Wc, bc, ws);

    int* cursor = (int*)(ws + OFF_CURSOR);
    int* bbase  = (int*)(ws + OFF_BBASE);
    int* basep  = (int*)(ws + OFF_BASE);
    int* csr    = (int*)(ws + OFF_CSR);
    uint_t* bin = (uint_t*)(ws + OFF_BIN);          // aliases xbf_enc head
    ushort_t* xbf_enc = (ushort_t*)(ws + OFF_XBF_ENC);
    ushort_t* xbf_pat = (ushort_t*)(ws + OFF_XBF_PAT);

    // Phase 1: bin edges into coarse dst buckets (245 blocks, 8192 edges each)
    int nchunks = (2 * NE + CH - 1) / CH;   // 245
    bin_kernel<<<nchunks, 256, 0, stream>>>(src_pe, dst_pe, src_ep, dst_ep,
                                            cursor, bin);

    // bucket prefix scan (1 block) -> bbase; also base[N_TOT]=2M
    bucketscan_kernel<<<1, 256, 0, stream>>>(cursor, bbase, basep);

    // Phase 2: per-bucket counting sort -> csr + base (fully coalesced writes)
    csrbuild_kernel<<<NB, 256, 0, stream>>>(bin, cursor, bbase, basep, csr);

    // bf16 feature copies -- AFTER csrbuild (xbf_enc overlays the dead bin)
    cvt_bf16_all_kernel<<<2048, 256, 0, stream>>>(x_enc, x_pat, xbf_enc, xbf_pat);

    const ushort_t* frags = (const ushort_t*)(ws + OFF_FRAGS);

    // patient transform (ep half) -> s_pat; Wl_ep1/Wr_ep1, cvec=wl2c
    int pat_waves = N_PAT / 16;   // 6250
    transform_fused_kernel<<<1024, 256, 0, stream>>>(
        xbf_enc, csr, basep + N_ENC, xbf_pat,
        frags + 2 * 8192, frags + 3 * 8192, b_ep1, ws + OFF_WL2C,
        nullptr, nullptr, ws + OFF_SPAT, pat_waves, 0);

    // encounter transform (pe half + layer-2 scalar gather) -> logits
    int enc_waves = N_ENC / 16;   // 31250
    transform_fused_kernel<<<2048, 256, 0, stream>>>(
        xbf_pat, csr, basep, xbf_enc,
        frags + 0 * 8192, frags + 1 * 8192, b_pe1, ws + OFF_WR2C,
        ws + OFF_SPAT, ws + OFF_C0, out, enc_waves, 1);
}

// Round 7
// 478.395 us; speedup vs baseline: 1.3664x; 1.0559x over previous
//
#include <hip/hip_runtime.h>
#include <hip/hip_bf16.h>

// Problem constants (from reference)
#define N_ENC 500000
#define N_PAT 100000
#define N_TOT 600000
#define D 64
#define HID 128
#define NE 1000000

// CSR-build binning geometry.
// enc buckets: 2048 nodes each (deg~2 -> mean 4096 edges/bucket, sd ~64)
// pat buckets: 512 nodes each (deg~10 -> mean 5120 edges/bucket, sd ~72)
// CAP 8192 is mean + >40 sd for both: overflow statistically impossible.
#define NB_ENC 245          // ceil(500000/2048)
#define NB 441              // 245 enc + 196 pat (ceil(100000/512))
#define CAP 8192            // per-bucket capacity (entries)
#define CH 8192             // edges per bin-kernel block

typedef unsigned short ushort_t;
typedef unsigned int uint_t;
typedef __attribute__((ext_vector_type(8))) short bfrag8;   // 8 x bf16 (4 VGPRs)
typedef __attribute__((ext_vector_type(4))) float f32x4;

// Workspace layout (float units). Zeroed region first (one tiny memset).
// High-water mark 21.92M floats (87.7 MB), below the proven-good 24.32M.
// KEY ALIASING: bin overlays the head of xbf_enc. bin is live only during
// bin->csrbuild; xbf_enc is written by cvt AFTER csrbuild (stream-ordered).
#define OFF_CURSOR   0              // NB ints (bucket fill cursors; pad 512)
#define ZERO_FLOATS  512
#define OFF_BBASE    512            // NB+1 ints (pad 512)
#define OFF_BASE     1024           // 600,001 ints (pad 600,032)
#define OFF_CSR      601056         // 2,000,000 ints
#define OFF_XBF_ENC  2601056        // 500,000*64 bf16 = 16,000,000 floats
#define OFF_BIN      2601056        // aliases xbf_enc head: 441*8192 = 3,612,672
#define OFF_XBF_PAT  18601056       // 100,000*64 bf16 = 3,200,000 floats
#define OFF_SPAT     21801056       // 100,000
#define OFF_FRAGS    21901056       // 4 matrices * 8192 ushort = 16,384 floats
#define OFF_WL2C     21917440       // 128
#define OFF_WR2C     21917568       // 128
#define OFF_C0       21917696       // 64
// end 21,917,760 floats = 87.7 MB

__device__ inline ushort_t f2bf(float x) {
    // round-to-nearest-even f32 -> bf16
    uint_t u = __float_as_uint(x);
    u += 0x7fffu + ((u >> 16) & 1u);
    return (ushort_t)(u >> 16);
}

// ---------------- Prep (weights -> MFMA fragments; layer-2 collapse) --------
__global__ __launch_bounds__(256) void prep_kernel(
    const float* __restrict__ Wl_pe1, const float* __restrict__ Wr_pe1,
    const float* __restrict__ Wl_ep1, const float* __restrict__ Wr_ep1,
    const float* __restrict__ Wl_pe2, const float* __restrict__ Wr_pe2,
    const float* __restrict__ b_pe2, const float* __restrict__ Wc,
    const float* __restrict__ bc, float* __restrict__ ws)
{
    int t = blockIdx.x * blockDim.x + threadIdx.x;
    const int total = 4 * 8192;
    ushort_t* fr = (ushort_t*)(ws + OFF_FRAGS);
    for (int i = t; i < total; i += gridDim.x * blockDim.x) {
        int mtx = i >> 13;
        int r = i & 8191;
        int jj = r & 7;
        int l = (r >> 3) & 63;
        int ft = r >> 9;          // 0..15 = jt*2+kt
        int kt = ft & 1;
        int jt = ft >> 1;
        int k = kt * 32 + (l >> 4) * 8 + jj;
        int j = jt * 16 + (l & 15);
        const float* W = (mtx == 0) ? Wl_pe1 : (mtx == 1) ? Wr_pe1
                       : (mtx == 2) ? Wl_ep1 : Wr_ep1;
        fr[i] = f2bf(W[k * HID + j]);
    }
    if (blockIdx.x == 0) {
        int tid = threadIdx.x;
        if (tid < HID) {
            float s1 = 0.f, s2 = 0.f;
            for (int j = 0; j < HID; j++) {
                float wc = Wc[j];
                s1 += Wl_pe2[tid * HID + j] * wc;
                s2 += Wr_pe2[tid * HID + j] * wc;
            }
            ws[OFF_WL2C + tid] = s1;
            ws[OFF_WR2C + tid] = s2;
            if (tid == 0) {
                float c0 = bc[0];
                for (int j = 0; j < HID; j++) c0 += b_pe2[j] * Wc[j];
                ws[OFF_C0] = c0;
            }
        }
    }
}

// f32 -> bf16 conversion for BOTH feature matrices, grid-strided.
// MUST run after csrbuild (xbf_enc aliases the bin staging region).
__global__ __launch_bounds__(256) void cvt_bf16_all_kernel(
    const float* __restrict__ x_enc, const float* __restrict__ x_pat,
    ushort_t* __restrict__ xbf_enc, ushort_t* __restrict__ xbf_pat)
{
    const int n8_enc = N_ENC * D / 8;            // 4,000,000
    const int n8_tot = n8_enc + N_PAT * D / 8;   // 4,800,000
    int stride = gridDim.x * 256;
    for (int i = blockIdx.x * 256 + threadIdx.x; i < n8_tot; i += stride) {
        const float* in; ushort_t* outp; int j;
        if (i < n8_enc) { in = x_enc; outp = xbf_enc; j = i; }
        else            { in = x_pat; outp = xbf_pat; j = i - n8_enc; }
        const f32x4* p = (const f32x4*)(in + (size_t)j * 8);
        f32x4 v0 = p[0], v1 = p[1];
        uint4 o;
        o.x = (uint_t)f2bf(v0[0]) | ((uint_t)f2bf(v0[1]) << 16);
        o.y = (uint_t)f2bf(v0[2]) | ((uint_t)f2bf(v0[3]) << 16);
        o.z = (uint_t)f2bf(v1[0]) | ((uint_t)f2bf(v1[1]) << 16);
        o.w = (uint_t)f2bf(v1[2]) | ((uint_t)f2bf(v1[3]) << 16);
        *(uint4*)(outp + (size_t)j * 8) = o;
    }
}

// ---------------- CSR build via LDS-staged two-phase binning ----------------
// r4 lesson: scattered 4B csr stores cost a full 64B HBM line each
// (place_all: WRITE_SIZE 133MB for 8MB useful, 183us). Fix: stage in LDS,
// write only contiguous runs. Phase 1 bins edges into 441 coarse dst-range
// buckets; phase 2 counting-sorts each bucket in LDS and writes the final
// csr segment + base[] offsets fully coalesced.
// Entry packing: src (20 bits, <1M) | dst-local (<=11 bits) << 20.

__global__ __launch_bounds__(256) void bin_kernel(
    const int* __restrict__ src_pe, const int* __restrict__ dst_pe,
    const int* __restrict__ src_ep, const int* __restrict__ dst_ep,
    int* __restrict__ cursor, uint_t* __restrict__ bin)
{
    __shared__ int lhist[512];     // padded to 512 for pair-scan
    __shared__ int lbase[512];
    __shared__ int lcnt2[NB];
    __shared__ int gpos[NB];
    __shared__ int s[256];
    __shared__ uint_t lout[CH];
    int t = threadIdx.x;
    int e0 = blockIdx.x * CH;
    int n = min(CH, 2 * NE - e0);

    for (int i = t; i < 512; i += 256) lhist[i] = 0;
    for (int i = t; i < NB; i += 256) lcnt2[i] = 0;   // zero ALL NB counters
    __syncthreads();
    // pass A: bucket histogram (dst only)
    for (int i = t; i < n; i += 256) {
        int e = e0 + i;
        int dc = (e < NE) ? dst_pe[e] : N_ENC + dst_ep[e - NE];
        int b = (dc < N_ENC) ? (dc >> 11) : (NB_ENC + ((dc - N_ENC) >> 9));
        atomicAdd(&lhist[b], 1);
    }
    __syncthreads();
    // exclusive scan of lhist[0..511]: pair-compress to 256 + Hillis-Steele
    int a0 = lhist[2 * t], a1 = lhist[2 * t + 1];
    s[t] = a0 + a1;
    __syncthreads();
    for (int off = 1; off < 256; off <<= 1) {
        int u = (t >= off) ? s[t - off] : 0;
        __syncthreads();
        s[t] += u;
        __syncthreads();
    }
    int ex = s[t] - a0 - a1;
    lbase[2 * t] = ex;
    lbase[2 * t + 1] = ex + a0;
    __syncthreads();
    // reserve global space (one atomic per nonempty bucket per block)
    for (int b = t; b < NB; b += 256) {
        int c = lhist[b];
        if (c) gpos[b] = atomicAdd(&cursor[b], c);
    }
    __syncthreads();
    // pass B: scatter into LDS, bucket-sorted
    for (int i = t; i < n; i += 256) {
        int e = e0 + i;
        int dc, sv;
        if (e < NE) { dc = dst_pe[e]; sv = src_pe[e]; }
        else { dc = N_ENC + dst_ep[e - NE]; sv = src_ep[e - NE]; }
        int b, loc;
        if (dc < N_ENC) { b = dc >> 11; loc = dc & 2047; }
        else { b = NB_ENC + ((dc - N_ENC) >> 9); loc = (dc - N_ENC) & 511; }
        int r = atomicAdd(&lcnt2[b], 1);
        lout[lbase[b] + r] = (uint_t)sv | ((uint_t)loc << 20);
    }
    __syncthreads();
    // copy runs to global bucket regions (contiguous per run)
    int wv = t >> 6, ln = t & 63;
    for (int b = wv; b < NB; b += 4) {
        int c = lhist[b];
        if (!c) continue;
        int gp = gpos[b];
        int c2 = min(c, CAP - gp);   // defensive clamp (overflow ~impossible)
        if (c2 <= 0) continue;
        uint_t* dstp = bin + (size_t)b * CAP + gp;
        const uint_t* srcp = lout + lbase[b];
        for (int k = ln; k < c2; k += 64) dstp[k] = srcp[k];
    }
}

__global__ __launch_bounds__(256) void bucketscan_kernel(
    const int* __restrict__ cursor, int* __restrict__ bbase,
    int* __restrict__ base)
{
    __shared__ int s[256];
    __shared__ int c2[512];
    int t = threadIdx.x;
    for (int i = t; i < 512; i += 256) c2[i] = (i < NB) ? min(cursor[i], CAP) : 0;
    __syncthreads();
    int a0 = c2[2 * t], a1 = c2[2 * t + 1];
    s[t] = a0 + a1;
    __syncthreads();
    for (int off = 1; off < 256; off <<= 1) {
        int u = (t >= off) ? s[t - off] : 0;
        __syncthreads();
        s[t] += u;
        __syncthreads();
    }
    int ex = s[t] - a0 - a1;
    if (2 * t < NB) bbase[2 * t] = ex;
    if (2 * t + 1 < NB) bbase[2 * t + 1] = ex + a0;
    if (t == 255) { bbase[NB] = s[t]; base[N_TOT] = s[t]; }
}

// one block per bucket: LDS counting sort by exact dst; coalesced csr+base out
__global__ __launch_bounds__(256) void csrbuild_kernel(
    const uint_t* __restrict__ bin, const int* __restrict__ cursor,
    const int* __restrict__ bbase, int* __restrict__ base,
    int* __restrict__ csr)
{
    __shared__ int h[2048];
    __shared__ int nb_[2048];
    __shared__ int s[256];
    __shared__ uint_t lout[CAP];
    int b = blockIdx.x;
    int t = threadIdx.x;
    int cnt = min(cursor[b], CAP);
    int nodes_base, nnodes;
    if (b < NB_ENC) { nodes_base = b << 11; nnodes = min(2048, N_ENC - nodes_base); }
    else { nodes_base = N_ENC + ((b - NB_ENC) << 9); nnodes = min(512, N_TOT - nodes_base); }
    const uint_t* reg = bin + (size_t)b * CAP;

    for (int i = t; i < 2048; i += 256) h[i] = 0;
    __syncthreads();
    for (int i = t; i < cnt; i += 256) atomicAdd(&h[reg[i] >> 20], 1);
    __syncthreads();
    // exclusive scan of h[0..2047]: 8 serial per thread + block scan
    int loc[8];
    int sum = 0;
#pragma unroll
    for (int j = 0; j < 8; j++) { loc[j] = sum; sum += h[8 * t + j]; }
    s[t] = sum;
    __syncthreads();
    for (int off = 1; off < 256; off <<= 1) {
        int u = (t >= off) ? s[t - off] : 0;
        __syncthreads();
        s[t] += u;
        __syncthreads();
    }
    int ex = s[t] - sum;
#pragma unroll
    for (int j = 0; j < 8; j++) nb_[8 * t + j] = ex + loc[j];
    __syncthreads();
    // write global CSR row offsets for this bucket's nodes (coalesced)
    int gb = bbase[b];
    for (int i = t; i < nnodes; i += 256) base[nodes_base + i] = gb + nb_[i];
    // re-zero h as rank counters
    for (int i = t; i < 2048; i += 256) h[i] = 0;
    __syncthreads();
    for (int i = t; i < cnt; i += 256) {
        uint_t p = reg[i];
        int lc = p >> 20;
        int r = atomicAdd(&h[lc], 1);
        lout[nb_[lc] + r] = p & 0xFFFFFu;
    }
    __syncthreads();
    for (int k = t; k < cnt; k += 256) csr[gb + k] = (int)lout[k];
}

// ---------------- Fused gather + MFMA transform -----------------------------
// One wave = 16 consecutive nodes, NON-persistent (r6 lesson: the persistent
// loop pushed VGPR 56->144, occupancy 40%->10.2%, dur 86.6->112us -- for this
// latency-bound gather, occupancy is the controlling variable and lowest-VGPR
// wins; measured ladder r0/r1/r3/r6 = 101/91.7/86.6/112us at 60/72/56/144
// VGPR). r3 structure restored: depth-4 gather (4 csr loads, then 8 row-loads
// in flight, then predicated accumulate), x0/x1 hoisted, bias/cvec loaded in
// the EPILOGUE (keeps them out of the gather loop's live range).
//   zL = sum_edges x_src @ Wl ; zR = x_dst @ Wr
//   z  = zL*invc + zR + bias ; out = sum_j relu(z)*cvec[j] (+ sa*invc + c0)
// A-frag: lane holds A[m=lane&15][k=(lane>>4)*8+jj]
// B-frag: lane holds B[k=(lane>>4)*8+jj][n=lane&15] (pre-packed)
// C/D: col(j)=lane&15, row(node)=(lane>>4)*4+reg (m89/m91-verified)
// NOTE: no __launch_bounds__ min-waves: (256,8) forced scratch spill
// (VGPR 32, WRITE_SIZE 2MB->252MB, +57us -- round-2 lesson).
__global__ __launch_bounds__(256) void transform_fused_kernel(
    const ushort_t* __restrict__ xsrc, const int* __restrict__ csr,
    const int* __restrict__ base, const ushort_t* __restrict__ xdst,
    const ushort_t* __restrict__ fragWl, const ushort_t* __restrict__ fragWr,
    const float* __restrict__ bias, const float* __restrict__ cvec,
    const float* __restrict__ sval, const float* __restrict__ c0p,
    float* __restrict__ out, int nwaves, int add_extra)
{
    int wid = blockIdx.x * 4 + (threadIdx.x >> 6);
    if (wid >= nwaves) return;
    int l = threadIdx.x & 63;
    int m = l & 15;
    int q = l >> 4;
    int nb = wid * 16;
    int row = nb + m;

    int s0 = base[row], s1 = base[row + 1];
    float degf = (float)(s1 - s0);

    // dst-feature frags: issued before the gather so they fly under it
    const ushort_t* xd = xdst + (size_t)row * D;
    bfrag8 x0 = *(const bfrag8*)(xd + q * 8);
    bfrag8 x1 = *(const bfrag8*)(xd + 32 + q * 8);

    // gather-accumulate this lane's 16 A elements (k = q*8.., 32+q*8..)
    float accf[16];
#pragma unroll
    for (int i = 0; i < 16; i++) accf[i] = 0.f;
    float sa = 0.f;

    int s1m1 = s1 - 1;
    for (int e = s0; e < s1; e += 4) {
        int sidx[4];
#pragma unroll
        for (int i = 0; i < 4; i++) {
            int ee = e + i;
            sidx[i] = csr[ee < s1m1 ? ee : s1m1];
        }
        uint4 w0[4], w1[4];
        float sv[4];
#pragma unroll
        for (int i = 0; i < 4; i++) {
            const uint_t* xr = (const uint_t*)(xsrc + (size_t)sidx[i] * D);
            w0[i] = *(const uint4*)(xr + q * 4);
            w1[i] = *(const uint4*)(xr + 16 + q * 4);
            sv[i] = (add_extra && q == 0) ? sval[sidx[i]] : 0.f;
        }
#pragma unroll
        for (int i = 0; i < 4; i++) {
            if (e + i < s1) {
                uint_t dw[8] = {w0[i].x, w0[i].y, w0[i].z, w0[i].w,
                                w1[i].x, w1[i].y, w1[i].z, w1[i].w};
#pragma unroll
                for (int k = 0; k < 8; k++) {
                    accf[2 * k]     += __uint_as_float(dw[k] << 16);
                    accf[2 * k + 1] += __uint_as_float(dw[k] & 0xffff0000u);
                }
                sa += sv[i];
            }
        }
    }

    bfrag8 a0, a1;
#pragma unroll
    for (int i = 0; i < 8; i++) {
        a0[i] = (short)f2bf(accf[i]);
        a1[i] = (short)f2bf(accf[8 + i]);
    }

    // bias/cvec in the EPILOGUE (out of the gather loop's live range)
    float bias_v[8], cvec_v[8];
#pragma unroll
    for (int jt = 0; jt < 8; jt++) {
        bias_v[jt] = bias[jt * 16 + m];
        cvec_v[jt] = cvec[jt * 16 + m];
    }

    // invc for the 4 C-rows (nodes nb+q*4+r) this lane holds
    f32x4 invc4;
#pragma unroll
    for (int r = 0; r < 4; r++) {
        float dg = __shfl(degf, q * 4 + r);  // lanes 0..15 hold node degs
        invc4[r] = 1.0f / fmaxf(dg, 1.0f);
    }

    f32x4 p = {0.f, 0.f, 0.f, 0.f};
#pragma unroll
    for (int jt = 0; jt < 8; jt++) {
        const bfrag8* bl0 = (const bfrag8*)(fragWl + ((size_t)(jt * 2 + 0) * 64 + l) * 8);
        const bfrag8* bl1 = (const bfrag8*)(fragWl + ((size_t)(jt * 2 + 1) * 64 + l) * 8);
        const bfrag8* br0 = (const bfrag8*)(fragWr + ((size_t)(jt * 2 + 0) * 64 + l) * 8);
        const bfrag8* br1 = (const bfrag8*)(fragWr + ((size_t)(jt * 2 + 1) * 64 + l) * 8);
        f32x4 accl = {0.f, 0.f, 0.f, 0.f};
        f32x4 accr = {0.f, 0.f, 0.f, 0.f};
        accl = __builtin_amdgcn_mfma_f32_16x16x32_bf16(a0, *bl0, accl, 0, 0, 0);
        accl = __builtin_amdgcn_mfma_f32_16x16x32_bf16(a1, *bl1, accl, 0, 0, 0);
        accr = __builtin_amdgcn_mfma_f32_16x16x32_bf16(x0, *br0, accr, 0, 0, 0);
        accr = __builtin_amdgcn_mfma_f32_16x16x32_bf16(x1, *br1, accr, 0, 0, 0);
        float bj = bias_v[jt], cj = cvec_v[jt];
#pragma unroll
        for (int r = 0; r < 4; r++) {
            float z = accl[r] * invc4[r] + accr[r] + bj;
            p[r] += fmaxf(z, 0.f) * cj;
        }
    }
#pragma unroll
    for (int off = 1; off < 16; off <<= 1) {
        p[0] += __shfl_xor(p[0], off, 16);
        p[1] += __shfl_xor(p[1], off, 16);
        p[2] += __shfl_xor(p[2], off, 16);
        p[3] += __shfl_xor(p[3], off, 16);
    }
    // layer-2 scalar sums for this quad's 4 nodes (from lanes 0..15; shuffles
    // OUTSIDE the divergent branch)
    f32x4 sa4;
#pragma unroll
    for (int r = 0; r < 4; r++) sa4[r] = __shfl(sa, q * 4 + r);
    if (m == 0) {
        int basen = nb + q * 4;
        f32x4 o = p;
        if (add_extra) {
            float c0 = c0p[0];
#pragma unroll
            for (int r = 0; r < 4; r++)
                o[r] += sa4[r] * invc4[r] + c0;
        }
        *(f32x4*)(out + basen) = o;   // coalesced vector store
    }
}

extern "C" void kernel_launch(void* const* d_in, const int* in_sizes, int n_in,
                              void* d_out, int out_size, void* d_ws, size_t ws_size,
                              hipStream_t stream)
{
    const float* x_enc  = (const float*)d_in[0];
    const float* x_pat  = (const float*)d_in[1];
    const int*   src_pe = (const int*)d_in[2];
    const int*   dst_pe = (const int*)d_in[3];
    const int*   src_ep = (const int*)d_in[4];
    const int*   dst_ep = (const int*)d_in[5];
    const float* Wl_pe1 = (const float*)d_in[6];
    const float* Wr_pe1 = (const float*)d_in[7];
    const float* b_pe1  = (const float*)d_in[8];
    const float* Wl_ep1 = (const float*)d_in[9];
    const float* Wr_ep1 = (const float*)d_in[10];
    const float* b_ep1  = (const float*)d_in[11];
    const float* Wl_pe2 = (const float*)d_in[12];
    const float* Wr_pe2 = (const float*)d_in[13];
    const float* b_pe2  = (const float*)d_in[14];
    const float* Wc = (const float*)d_in[18];
    const float* bc = (const float*)d_in[19];

    float* ws  = (float*)d_ws;
    float* out = (float*)d_out;

    // zero: bucket cursors only (2 KB)
    hipMemsetAsync(d_ws, 0, (size_t)ZERO_FLOATS * sizeof(float), stream);

    prep_kernel<<<128, 256, 0, stream>>>(Wl_pe1, Wr_pe1, Wl_ep1, Wr_ep1,
                                         Wl_pe2, Wr_pe2, b_pe2, Wc, bc, ws);

    int* cursor = (int*)(ws + OFF_CURSOR);
    int* bbase  = (int*)(ws + OFF_BBASE);
    int* basep  = (int*)(ws + OFF_BASE);
    int* csr    = (int*)(ws + OFF_CSR);
    uint_t* bin = (uint_t*)(ws + OFF_BIN);          // aliases xbf_enc head
    ushort_t* xbf_enc = (ushort_t*)(ws + OFF_XBF_ENC);
    ushort_t* xbf_pat = (ushort_t*)(ws + OFF_XBF_PAT);

    // Phase 1: bin edges into coarse dst buckets (245 blocks, 8192 edges each)
    int nchunks = (2 * NE + CH - 1) / CH;   // 245
    bin_kernel<<<nchunks, 256, 0, stream>>>(src_pe, dst_pe, src_ep, dst_ep,
                                            cursor, bin);

    // bucket prefix scan (1 block) -> bbase; also base[N_TOT]=2M
    bucketscan_kernel<<<1, 256, 0, stream>>>(cursor, bbase, basep);

    // Phase 2: per-bucket counting sort -> csr + base (fully coalesced writes)
    csrbuild_kernel<<<NB, 256, 0, stream>>>(bin, cursor, bbase, basep, csr);

    // bf16 feature copies -- AFTER csrbuild (xbf_enc overlays the dead bin)
    cvt_bf16_all_kernel<<<2048, 256, 0, stream>>>(x_enc, x_pat, xbf_enc, xbf_pat);

    const ushort_t* frags = (const ushort_t*)(ws + OFF_FRAGS);

    // patient transform (ep half) -> s_pat; Wl_ep1/Wr_ep1, cvec=wl2c
    int pat_waves = N_PAT / 16;   // 6250
    transform_fused_kernel<<<(pat_waves + 3) / 4, 256, 0, stream>>>(
        xbf_enc, csr, basep + N_ENC, xbf_pat,
        frags + 2 * 8192, frags + 3 * 8192, b_ep1, ws + OFF_WL2C,
        nullptr, nullptr, ws + OFF_SPAT, pat_waves, 0);

    // encounter transform (pe half + layer-2 scalar gather) -> logits
    int enc_waves = N_ENC / 16;   // 31250
    transform_fused_kernel<<<(enc_waves + 3) / 4, 256, 0, stream>>>(
        xbf_pat, csr, basep, xbf_enc,
        frags + 0 * 8192, frags + 1 * 8192, b_pe1, ws + OFF_WR2C,
        ws + OFF_SPAT, ws + OFF_C0, out, enc_waves, 1);
}

// Round 8
// 449.479 us; speedup vs baseline: 1.4543x; 1.0643x over previous
//
#include <hip/hip_runtime.h>
#include <hip/hip_bf16.h>

// Problem constants (from reference)
#define N_ENC 500000
#define N_PAT 100000
#define N_TOT 600000
#define D 64
#define HID 128
#define NE 1000000

// CSR-build binning geometry.
// enc buckets: 2048 nodes each (deg~2 -> mean 4096 edges/bucket, sd ~64)
// pat buckets: 512 nodes each (deg~10 -> mean 5120 edges/bucket, sd ~72)
// CAP 8192 is mean + >40 sd for both: overflow statistically impossible.
#define NB_ENC 245          // ceil(500000/2048)
#define NB 441              // 245 enc + 196 pat (ceil(100000/512))
#define CAP 8192            // per-bucket capacity (entries)
#define CH 8192             // edges per bin-kernel block
#define NCHUNKS 245         // ceil(2*NE/CH)
#define PREP_BLOCKS 33      // 32 frag-fill blocks + 1 collapse block

typedef unsigned short ushort_t;
typedef unsigned int uint_t;
typedef __attribute__((ext_vector_type(8))) short bfrag8;   // 8 x bf16 (4 VGPRs)
typedef __attribute__((ext_vector_type(4))) float f32x4;

// Workspace layout (float units). Zeroed region first (one tiny memset).
// High-water mark 21.92M floats (87.7 MB), below the proven-good 24.32M.
// KEY ALIASING: bin overlays the head of xbf_enc. bin is live only during
// bin->csrbuild; xbf_enc is written by cvt AFTER csrbuild (stream-ordered).
#define OFF_CURSOR   0              // NB ints (bucket fill cursors; pad 512)
#define ZERO_FLOATS  512
#define OFF_BASE     1024           // 600,001 ints (pad 600,032)
#define OFF_CSR      601056        // 2,000,000 ints
#define OFF_XBF_ENC  2601056        // 500,000*64 bf16 = 16,000,000 floats
#define OFF_BIN      2601056        // aliases xbf_enc head: 441*8192 = 3,612,672
#define OFF_XBF_PAT  18601056       // 100,000*64 bf16 = 3,200,000 floats
#define OFF_SPAT     21801056       // 100,000
#define OFF_FRAGS    21901056       // 4 matrices * 8192 ushort = 16,384 floats
#define OFF_WL2C     21917440       // 128
#define OFF_WR2C     21917568       // 128
#define OFF_C0       21917696       // 64
// end 21,917,760 floats = 87.7 MB

__device__ inline ushort_t f2bf(float x) {
    // round-to-nearest-even f32 -> bf16
    uint_t u = __float_as_uint(x);
    u += 0x7fffu + ((u >> 16) & 1u);
    return (ushort_t)(u >> 16);
}

// f32 -> bf16 conversion for BOTH feature matrices, grid-strided.
// MUST run after csrbuild (xbf_enc aliases the bin staging region).
__global__ __launch_bounds__(256) void cvt_bf16_all_kernel(
    const float* __restrict__ x_enc, const float* __restrict__ x_pat,
    ushort_t* __restrict__ xbf_enc, ushort_t* __restrict__ xbf_pat)
{
    const int n8_enc = N_ENC * D / 8;            // 4,000,000
    const int n8_tot = n8_enc + N_PAT * D / 8;   // 4,800,000
    int stride = gridDim.x * 256;
    for (int i = blockIdx.x * 256 + threadIdx.x; i < n8_tot; i += stride) {
        const float* in; ushort_t* outp; int j;
        if (i < n8_enc) { in = x_enc; outp = xbf_enc; j = i; }
        else            { in = x_pat; outp = xbf_pat; j = i - n8_enc; }
        const f32x4* p = (const f32x4*)(in + (size_t)j * 8);
        f32x4 v0 = p[0], v1 = p[1];
        uint4 o;
        o.x = (uint_t)f2bf(v0[0]) | ((uint_t)f2bf(v0[1]) << 16);
        o.y = (uint_t)f2bf(v0[2]) | ((uint_t)f2bf(v0[3]) << 16);
        o.z = (uint_t)f2bf(v1[0]) | ((uint_t)f2bf(v1[1]) << 16);
        o.w = (uint_t)f2bf(v1[2]) | ((uint_t)f2bf(v1[3]) << 16);
        *(uint4*)(outp + (size_t)j * 8) = o;
    }
}

// ---------------- bin + prep fused (saves one launch) -----------------------
// Blocks [0, NCHUNKS): LDS-staged edge binning into 441 coarse dst buckets.
// Blocks [NCHUNKS, NCHUNKS+PREP_BLOCKS): weight->fragment prep + layer-2
// collapse (independent outputs: bin region vs frags/wl2c/wr2c/c0).
// r4 lesson: scattered 4B csr stores cost a full 64B HBM line each (place_all:
// WRITE_SIZE 133MB for 8MB useful, 183us) -> stage in LDS, write runs.
// Entry packing: src (20 bits, <1M) | dst-local (<=11 bits) << 20.
__global__ __launch_bounds__(256) void bin_prep_kernel(
    const int* __restrict__ src_pe, const int* __restrict__ dst_pe,
    const int* __restrict__ src_ep, const int* __restrict__ dst_ep,
    int* __restrict__ cursor, uint_t* __restrict__ bin,
    const float* __restrict__ Wl_pe1, const float* __restrict__ Wr_pe1,
    const float* __restrict__ Wl_ep1, const float* __restrict__ Wr_ep1,
    const float* __restrict__ Wl_pe2, const float* __restrict__ Wr_pe2,
    const float* __restrict__ b_pe2, const float* __restrict__ Wc,
    const float* __restrict__ bc, float* __restrict__ ws)
{
    __shared__ int lhist[512];     // padded to 512 for pair-scan
    __shared__ int lbase[512];
    __shared__ int lcnt2[NB];
    __shared__ int gpos[NB];
    __shared__ int s[256];
    __shared__ uint_t lout[CH];
    int t = threadIdx.x;

    if (blockIdx.x >= NCHUNKS) {
        // ---- prep path ----
        int pb = blockIdx.x - NCHUNKS;
        ushort_t* fr = (ushort_t*)(ws + OFF_FRAGS);
        if (pb < 32) {
            const int total = 4 * 8192;
            for (int i = pb * 256 + t; i < total; i += 32 * 256) {
                int mtx = i >> 13;
                int r = i & 8191;
                int jj = r & 7;
                int l = (r >> 3) & 63;
                int ft = r >> 9;          // 0..15 = jt*2+kt
                int kt = ft & 1;
                int jt = ft >> 1;
                int k = kt * 32 + (l >> 4) * 8 + jj;
                int j = jt * 16 + (l & 15);
                const float* W = (mtx == 0) ? Wl_pe1 : (mtx == 1) ? Wr_pe1
                               : (mtx == 2) ? Wl_ep1 : Wr_ep1;
                fr[i] = f2bf(W[k * HID + j]);
            }
        } else {
            // layer-2 collapse
            if (t < HID) {
                float s1 = 0.f, s2 = 0.f;
                for (int j = 0; j < HID; j++) {
                    float wc = Wc[j];
                    s1 += Wl_pe2[t * HID + j] * wc;
                    s2 += Wr_pe2[t * HID + j] * wc;
                }
                ws[OFF_WL2C + t] = s1;
                ws[OFF_WR2C + t] = s2;
                if (t == 0) {
                    float c0 = bc[0];
                    for (int j = 0; j < HID; j++) c0 += b_pe2[j] * Wc[j];
                    ws[OFF_C0] = c0;
                }
            }
        }
        return;
    }

    // ---- bin path ----
    int e0 = blockIdx.x * CH;
    int n = min(CH, 2 * NE - e0);

    for (int i = t; i < 512; i += 256) lhist[i] = 0;
    for (int i = t; i < NB; i += 256) lcnt2[i] = 0;   // zero ALL NB counters
    __syncthreads();
    // pass A: bucket histogram (dst only)
    for (int i = t; i < n; i += 256) {
        int e = e0 + i;
        int dc = (e < NE) ? dst_pe[e] : N_ENC + dst_ep[e - NE];
        int b = (dc < N_ENC) ? (dc >> 11) : (NB_ENC + ((dc - N_ENC) >> 9));
        atomicAdd(&lhist[b], 1);
    }
    __syncthreads();
    // exclusive scan of lhist[0..511]: pair-compress to 256 + Hillis-Steele
    int a0 = lhist[2 * t], a1 = lhist[2 * t + 1];
    s[t] = a0 + a1;
    __syncthreads();
    for (int off = 1; off < 256; off <<= 1) {
        int u = (t >= off) ? s[t - off] : 0;
        __syncthreads();
        s[t] += u;
        __syncthreads();
    }
    int ex = s[t] - a0 - a1;
    lbase[2 * t] = ex;
    lbase[2 * t + 1] = ex + a0;
    __syncthreads();
    // reserve global space (one atomic per nonempty bucket per block)
    for (int b = t; b < NB; b += 256) {
        int c = lhist[b];
        if (c) gpos[b] = atomicAdd(&cursor[b], c);
    }
    __syncthreads();
    // pass B: scatter into LDS, bucket-sorted
    for (int i = t; i < n; i += 256) {
        int e = e0 + i;
        int dc, sv;
        if (e < NE) { dc = dst_pe[e]; sv = src_pe[e]; }
        else { dc = N_ENC + dst_ep[e - NE]; sv = src_ep[e - NE]; }
        int b, loc;
        if (dc < N_ENC) { b = dc >> 11; loc = dc & 2047; }
        else { b = NB_ENC + ((dc - N_ENC) >> 9); loc = (dc - N_ENC) & 511; }
        int r = atomicAdd(&lcnt2[b], 1);
        lout[lbase[b] + r] = (uint_t)sv | ((uint_t)loc << 20);
    }
    __syncthreads();
    // copy runs to global bucket regions (contiguous per run)
    int wv = t >> 6, ln = t & 63;
    for (int b = wv; b < NB; b += 4) {
        int c = lhist[b];
        if (!c) continue;
        int gp = gpos[b];
        int c2 = min(c, CAP - gp);   // defensive clamp (overflow ~impossible)
        if (c2 <= 0) continue;
        uint_t* dstp = bin + (size_t)b * CAP + gp;
        const uint_t* srcp = lout + lbase[b];
        for (int k = ln; k < c2; k += 64) dstp[k] = srcp[k];
    }
}

// one block per bucket: in-LDS bucket prefix scan (replaces the separate
// bucketscan launch -- 441 redundant 441-elem scans are ~free), then LDS
// counting sort by exact dst; coalesced csr+base writes.
__global__ __launch_bounds__(256) void csrbuild_kernel(
    const uint_t* __restrict__ bin, const int* __restrict__ cursor,
    int* __restrict__ base, int* __restrict__ csr)
{
    __shared__ int h[2048];
    __shared__ int nb_[2048];
    __shared__ int s[256];
    __shared__ int cs[512];
    __shared__ uint_t lout[CAP];
    int b = blockIdx.x;
    int t = threadIdx.x;

    // bucket prefix scan (exclusive) over min(cursor, CAP)
    for (int i = t; i < 512; i += 256) cs[i] = (i < NB) ? min(cursor[i], CAP) : 0;
    __syncthreads();
    int ca0 = cs[2 * t], ca1 = cs[2 * t + 1];
    s[t] = ca0 + ca1;
    __syncthreads();
    for (int off = 1; off < 256; off <<= 1) {
        int u = (t >= off) ? s[t - off] : 0;
        __syncthreads();
        s[t] += u;
        __syncthreads();
    }
    int cex = s[t] - ca0 - ca1;
    int ctotal = s[255];
    __syncthreads();   // s reused below; cs rewritten now
    cs[2 * t] = cex;
    cs[2 * t + 1] = cex + ca0;
    __syncthreads();
    int gb = cs[b];
    if (b == 0 && t == 0) base[N_TOT] = ctotal;

    int cnt = min(cursor[b], CAP);
    int nodes_base, nnodes;
    if (b < NB_ENC) { nodes_base = b << 11; nnodes = min(2048, N_ENC - nodes_base); }
    else { nodes_base = N_ENC + ((b - NB_ENC) << 9); nnodes = min(512, N_TOT - nodes_base); }
    const uint_t* reg = bin + (size_t)b * CAP;

    for (int i = t; i < 2048; i += 256) h[i] = 0;
    __syncthreads();
    for (int i = t; i < cnt; i += 256) atomicAdd(&h[reg[i] >> 20], 1);
    __syncthreads();
    // exclusive scan of h[0..2047]: 8 serial per thread + block scan
    int loc[8];
    int sum = 0;
#pragma unroll
    for (int j = 0; j < 8; j++) { loc[j] = sum; sum += h[8 * t + j]; }
    s[t] = sum;
    __syncthreads();
    for (int off = 1; off < 256; off <<= 1) {
        int u = (t >= off) ? s[t - off] : 0;
        __syncthreads();
        s[t] += u;
        __syncthreads();
    }
    int ex = s[t] - sum;
#pragma unroll
    for (int j = 0; j < 8; j++) nb_[8 * t + j] = ex + loc[j];
    __syncthreads();
    // write global CSR row offsets for this bucket's nodes (coalesced)
    for (int i = t; i < nnodes; i += 256) base[nodes_base + i] = gb + nb_[i];
    // re-zero h as rank counters
    for (int i = t; i < 2048; i += 256) h[i] = 0;
    __syncthreads();
    for (int i = t; i < cnt; i += 256) {
        uint_t p = reg[i];
        int lc = p >> 20;
        int r = atomicAdd(&h[lc], 1);
        lout[nb_[lc] + r] = p & 0xFFFFFu;
    }
    __syncthreads();
    for (int k = t; k < cnt; k += 256) csr[gb + k] = (int)lout[k];
}

// ---------------- Fused gather + MFMA transform -----------------------------
// One wave = 16 consecutive nodes, NON-persistent. Body mirrors r3 EXACTLY
// (the only configuration measured at 56 VGPR / 40% occ / 86.6us): bias/cvec
// hoisted BEFORE the gather, r3's sval conditional structure. r7's epilogue-
// deferred variant came out 76 VGPR / 30% / 97.4us -- allocation is sensitive
// to these orderings; trust the measured ladder, not the heuristic
// (r0/r1/r3/r6/r7 = 101/91.7/86.6/112/97.4us at 60/72/56/144/76 VGPR).
// Depth-4 gather: 4 csr loads, then 8 row-loads in flight, then predicated
// accumulate. NO persistent loop (r6: VGPR 144, occ 10%). NO __launch_bounds__
// min-waves (r2: forced spill, WRITE_SIZE 252MB).
//   zL = sum_edges x_src @ Wl ; zR = x_dst @ Wr
//   z  = zL*invc + zR + bias ; out = sum_j relu(z)*cvec[j] (+ sa*invc + c0)
// A-frag: lane holds A[m=lane&15][k=(lane>>4)*8+jj]
// B-frag: lane holds B[k=(lane>>4)*8+jj][n=lane&15] (pre-packed)
// C/D: col(j)=lane&15, row(node)=(lane>>4)*4+reg (m89/m91-verified)
__global__ __launch_bounds__(256) void transform_fused_kernel(
    const ushort_t* __restrict__ xsrc, const int* __restrict__ csr,
    const int* __restrict__ base, const ushort_t* __restrict__ xdst,
    const ushort_t* __restrict__ fragWl, const ushort_t* __restrict__ fragWr,
    const float* __restrict__ bias, const float* __restrict__ cvec,
    const float* __restrict__ sval, const float* __restrict__ c0p,
    float* __restrict__ out, int nwaves, int add_extra)
{
    int wid = blockIdx.x * 4 + (threadIdx.x >> 6);
    if (wid >= nwaves) return;
    int l = threadIdx.x & 63;
    int m = l & 15;
    int q = l >> 4;
    int nb = wid * 16;
    int row = nb + m;

    int s0 = base[row], s1 = base[row + 1];
    float degf = (float)(s1 - s0);

    // dst-feature frags: issued before the gather so they fly under it
    const ushort_t* xd = xdst + (size_t)row * D;
    bfrag8 x0 = *(const bfrag8*)(xd + q * 8);
    bfrag8 x1 = *(const bfrag8*)(xd + 32 + q * 8);

    // bias/cvec BEFORE the gather (r3 ordering -- measured 56 VGPR)
    float bias_v[8], cvec_v[8];
#pragma unroll
    for (int jt = 0; jt < 8; jt++) {
        bias_v[jt] = bias[jt * 16 + m];
        cvec_v[jt] = cvec[jt * 16 + m];
    }

    // gather-accumulate this lane's 16 A elements (k = q*8.., 32+q*8..)
    float accf[16];
#pragma unroll
    for (int i = 0; i < 16; i++) accf[i] = 0.f;
    float sa = 0.f;

    int s1m1 = s1 - 1;
    for (int e = s0; e < s1; e += 4) {
        int sidx[4];
#pragma unroll
        for (int i = 0; i < 4; i++) {
            int ee = e + i;
            sidx[i] = csr[ee < s1m1 ? ee : s1m1];
        }
        uint4 w0[4], w1[4];
        float sv[4];
#pragma unroll
        for (int i = 0; i < 4; i++) {
            const uint_t* xr = (const uint_t*)(xsrc + (size_t)sidx[i] * D);
            w0[i] = *(const uint4*)(xr + q * 4);
            w1[i] = *(const uint4*)(xr + 16 + q * 4);
            if (add_extra) sv[i] = sval[sidx[i]];
        }
#pragma unroll
        for (int i = 0; i < 4; i++) {
            if (e + i < s1) {
                uint_t dw[8] = {w0[i].x, w0[i].y, w0[i].z, w0[i].w,
                                w1[i].x, w1[i].y, w1[i].z, w1[i].w};
#pragma unroll
                for (int k = 0; k < 8; k++) {
                    accf[2 * k]     += __uint_as_float(dw[k] << 16);
                    accf[2 * k + 1] += __uint_as_float(dw[k] & 0xffff0000u);
                }
                if (add_extra) sa += sv[i];
            }
        }
    }

    bfrag8 a0, a1;
#pragma unroll
    for (int i = 0; i < 8; i++) {
        a0[i] = (short)f2bf(accf[i]);
        a1[i] = (short)f2bf(accf[8 + i]);
    }

    // invc for the 4 C-rows (nodes nb+q*4+r) this lane holds
    f32x4 invc4;
#pragma unroll
    for (int r = 0; r < 4; r++) {
        float dg = __shfl(degf, q * 4 + r);  // lanes 0..15 hold node degs
        invc4[r] = 1.0f / fmaxf(dg, 1.0f);
    }

    f32x4 p = {0.f, 0.f, 0.f, 0.f};
#pragma unroll
    for (int jt = 0; jt < 8; jt++) {
        const bfrag8* bl0 = (const bfrag8*)(fragWl + ((size_t)(jt * 2 + 0) * 64 + l) * 8);
        const bfrag8* bl1 = (const bfrag8*)(fragWl + ((size_t)(jt * 2 + 1) * 64 + l) * 8);
        const bfrag8* br0 = (const bfrag8*)(fragWr + ((size_t)(jt * 2 + 0) * 64 + l) * 8);
        const bfrag8* br1 = (const bfrag8*)(fragWr + ((size_t)(jt * 2 + 1) * 64 + l) * 8);
        f32x4 accl = {0.f, 0.f, 0.f, 0.f};
        f32x4 accr = {0.f, 0.f, 0.f, 0.f};
        accl = __builtin_amdgcn_mfma_f32_16x16x32_bf16(a0, *bl0, accl, 0, 0, 0);
        accl = __builtin_amdgcn_mfma_f32_16x16x32_bf16(a1, *bl1, accl, 0, 0, 0);
        accr = __builtin_amdgcn_mfma_f32_16x16x32_bf16(x0, *br0, accr, 0, 0, 0);
        accr = __builtin_amdgcn_mfma_f32_16x16x32_bf16(x1, *br1, accr, 0, 0, 0);
        float bj = bias_v[jt], cj = cvec_v[jt];
#pragma unroll
        for (int r = 0; r < 4; r++) {
            float z = accl[r] * invc4[r] + accr[r] + bj;
            p[r] += fmaxf(z, 0.f) * cj;
        }
    }
#pragma unroll
    for (int off = 1; off < 16; off <<= 1) {
        p[0] += __shfl_xor(p[0], off, 16);
        p[1] += __shfl_xor(p[1], off, 16);
        p[2] += __shfl_xor(p[2], off, 16);
        p[3] += __shfl_xor(p[3], off, 16);
    }
    // layer-2 scalar sums for this quad's 4 nodes (from lanes 0..15; shuffles
    // OUTSIDE the divergent branch)
    f32x4 sa4;
#pragma unroll
    for (int r = 0; r < 4; r++) sa4[r] = __shfl(sa, q * 4 + r);
    if (m == 0) {
        int basen = nb + q * 4;
        f32x4 o = p;
        if (add_extra) {
            float c0 = c0p[0];
#pragma unroll
            for (int r = 0; r < 4; r++)
                o[r] += sa4[r] * invc4[r] + c0;
        }
        *(f32x4*)(out + basen) = o;   // coalesced vector store
    }
}

extern "C" void kernel_launch(void* const* d_in, const int* in_sizes, int n_in,
                              void* d_out, int out_size, void* d_ws, size_t ws_size,
                              hipStream_t stream)
{
    const float* x_enc  = (const float*)d_in[0];
    const float* x_pat  = (const float*)d_in[1];
    const int*   src_pe = (const int*)d_in[2];
    const int*   dst_pe = (const int*)d_in[3];
    const int*   src_ep = (const int*)d_in[4];
    const int*   dst_ep = (const int*)d_in[5];
    const float* Wl_pe1 = (const float*)d_in[6];
    const float* Wr_pe1 = (const float*)d_in[7];
    const float* b_pe1  = (const float*)d_in[8];
    const float* Wl_ep1 = (const float*)d_in[9];
    const float* Wr_ep1 = (const float*)d_in[10];
    const float* b_ep1  = (const float*)d_in[11];
    const float* Wl_pe2 = (const float*)d_in[12];
    const float* Wr_pe2 = (const float*)d_in[13];
    const float* b_pe2  = (const float*)d_in[14];
    const float* Wc = (const float*)d_in[18];
    const float* bc = (const float*)d_in[19];

    float* ws  = (float*)d_ws;
    float* out = (float*)d_out;

    // zero: bucket cursors only (2 KB)
    hipMemsetAsync(d_ws, 0, (size_t)ZERO_FLOATS * sizeof(float), stream);

    int* cursor = (int*)(ws + OFF_CURSOR);
    int* basep  = (int*)(ws + OFF_BASE);
    int* csr    = (int*)(ws + OFF_CSR);
    uint_t* bin = (uint_t*)(ws + OFF_BIN);          // aliases xbf_enc head
    ushort_t* xbf_enc = (ushort_t*)(ws + OFF_XBF_ENC);
    ushort_t* xbf_pat = (ushort_t*)(ws + OFF_XBF_PAT);

    // Phase 1: bin edges into coarse dst buckets + (fused) weight prep
    bin_prep_kernel<<<NCHUNKS + PREP_BLOCKS, 256, 0, stream>>>(
        src_pe, dst_pe, src_ep, dst_ep, cursor, bin,
        Wl_pe1, Wr_pe1, Wl_ep1, Wr_ep1, Wl_pe2, Wr_pe2, b_pe2, Wc, bc, ws);

    // Phase 2: per-bucket counting sort -> csr + base (fully coalesced
    // writes); bucket prefix scan fused in (each block scans 441 cursors)
    csrbuild_kernel<<<NB, 256, 0, stream>>>(bin, cursor, basep, csr);

    // bf16 feature copies -- AFTER csrbuild (xbf_enc overlays the dead bin)
    cvt_bf16_all_kernel<<<2048, 256, 0, stream>>>(x_enc, x_pat, xbf_enc, xbf_pat);

    const ushort_t* frags = (const ushort_t*)(ws + OFF_FRAGS);

    // patient transform (ep half) -> s_pat; Wl_ep1/Wr_ep1, cvec=wl2c
    int pat_waves = N_PAT / 16;   // 6250
    transform_fused_kernel<<<(pat_waves + 3) / 4, 256, 0, stream>>>(
        xbf_enc, csr, basep + N_ENC, xbf_pat,
        frags + 2 * 8192, frags + 3 * 8192, b_ep1, ws + OFF_WL2C,
        nullptr, nullptr, ws + OFF_SPAT, pat_waves, 0);

    // encounter transform (pe half + layer-2 scalar gather) -> logits
    int enc_waves = N_ENC / 16;   // 31250
    transform_fused_kernel<<<(enc_waves + 3) / 4, 256, 0, stream>>>(
        xbf_pat, csr, basep, xbf_enc,
        frags + 0 * 8192, frags + 1 * 8192, b_pe1, ws + OFF_WR2C,
        ws + OFF_SPAT, ws + OFF_C0, out, enc_waves, 1);
}